// Round 9
// baseline (77.881 us; speedup 1.0000x reference)
//
#include <hip/hip_runtime.h>
#include <math.h>

// Problem constants (fixed shapes from reference)
#define BATCH   8
#define HGRID   64
#define WGRID   64
#define DDIM    256
#define NPTS    1024
#define ROWS    65          // HGRID + 1 (NaN pad row 0)
#define COLS    65
#define KWIN    15          // (2*R_WIN+1)*(2*C_WIN+1) = 3*5
#define BN      (BATCH*NPTS)

#define PIDS_PER_BLK 8
#define THREADS      512    // 8 waves, 1 pid per wave in Phase B
#define PR_PITCH     260
#define CT_BLOCKS    (BN * DDIM / 1024)   // 2048

typedef __attribute__((ext_vector_type(8))) short bf16x8;
typedef __attribute__((ext_vector_type(4))) float f32x4;

// ---------------------------------------------------------------------------
// Kernel 1 (prep): split c_t -> CH/CL (bf16 hi + bf16 residual), and split +
// TRANSPOSE W_a -> WHT/WLT[d][c] so MFMA B-frags are 16B k-contiguous loads.
// Blocks 0..2047: c_t (256 thr x 4 floats). Blocks 2048..2303: W column d.
// ---------------------------------------------------------------------------
__global__ __launch_bounds__(256) void prep(const float* __restrict__ ct,
                                            const float* __restrict__ W,
                                            ushort* __restrict__ CH,
                                            ushort* __restrict__ CL,
                                            ushort* __restrict__ WHT,
                                            ushort* __restrict__ WLT) {
    const int bid = blockIdx.x;
    if (bid < CT_BLOCKS) {
        const int i = (bid * 256 + threadIdx.x) * 4;
        const float4 v = *reinterpret_cast<const float4*>(&ct[i]);
        const float f[4] = {v.x, v.y, v.z, v.w};
        ushort h[4], l[4];
        #pragma unroll
        for (int e = 0; e < 4; ++e) {
            const unsigned u = __float_as_uint(f[e]);
            h[e] = (ushort)(u >> 16);
            const float res = f[e] - __uint_as_float(u & 0xFFFF0000u);
            l[e] = (ushort)(__float_as_uint(res) >> 16);
        }
        *reinterpret_cast<ushort4*>(&CH[i]) = make_ushort4(h[0], h[1], h[2], h[3]);
        *reinterpret_cast<ushort4*>(&CL[i]) = make_ushort4(l[0], l[1], l[2], l[3]);
    } else {
        const int d = bid - CT_BLOCKS;
        const int c = threadIdx.x;
        const float f = W[c * DDIM + d];
        const unsigned u = __float_as_uint(f);
        const float res = f - __uint_as_float(u & 0xFFFF0000u);
        WHT[d * DDIM + c] = (ushort)(u >> 16);
        WLT[d * DDIM + c] = (ushort)(__float_as_uint(res) >> 16);
    }
}

// ---------------------------------------------------------------------------
// Kernel 2 (fused v5): per block of 8 points, 1 pid per wave.
//   Step 1: window geometry + PREFETCH all 15 q-gathers into registers.
//   Step 2 (Phase A): proj[8][256] = c_t rows x W_a via 3-term split-bf16
//     MFMA. Pre-converted operands: per kt = 6x uint4 loads + 6 MFMA, zero
//     conversion VALU. Gather latency hides behind this.
//   Step 3: barrier; dots vs proj (LDS), butterfly reduce, softmax,
//     weighted sum from registers, store.
// __launch_bounds__(512,4): 128-VGPR cap (est live ~115). Grid 1024 blocks.
// ---------------------------------------------------------------------------
__global__ __launch_bounds__(THREADS, 4) void fused_local_attn(
        const float* __restrict__ q,
        const float* __restrict__ p_t,
        const ushort* __restrict__ CH,
        const ushort* __restrict__ CL,
        const ushort* __restrict__ WHT,
        const ushort* __restrict__ WLT,
        float* __restrict__ out) {

    __shared__ __align__(16) float Pr[PIDS_PER_BLK][PR_PITCH]; // proj rows (8.3 KB)

    const int t    = threadIdx.x;
    const int w    = t >> 6;          // wave 0..7
    const int lane = t & 63;
    const int l15  = lane & 15;
    const int g    = lane >> 4;       // k-group 0..3
    const int pid0 = blockIdx.x * PIDS_PER_BLK;
    const int dq   = w * 32;          // this wave's 32-col d-slice
    const int pid  = pid0 + w;
    const int b    = pid >> 10;       // / NPTS

    // ---------------- Step 1: geometry + gather prefetch ----------------
    const float2 ppos = *reinterpret_cast<const float2*>(&p_t[pid * 2]);
    const float p0f = ppos.x;
    const float p1f = ppos.y;
    const int p0 = (int)p0f;
    const int p1 = (int)p1f;

    float re[3], ce[5];
    int rowidx[3], colidx[5];
    #pragma unroll
    for (int i = 0; i < 3; ++i) {
        int rr = p0 + i;
        rr = rr > ROWS ? ROWS : rr;
        rr = (rr == ROWS) ? 0 : rr;        // % ROWS
        rowidx[i] = rr;
        const float rf = (float)(rr - 1 > 0 ? rr - 1 : 0);
        const float dr = rf - p0f;         // / R_WIN (=1)
        re[i] = __expf(-2.0f * dr * dr);
    }
    #pragma unroll
    for (int j = 0; j < 5; ++j) {
        int cc = p1 + j - 1;
        cc = cc < 0 ? 0 : (cc > COLS ? COLS : cc);
        cc = (cc == COLS) ? 0 : cc;        // % COLS
        colidx[j] = cc;
        const float cf = (float)(cc - 1 > 0 ? cc - 1 : 0);
        const float dc = (cf - p1f) * 0.5f; // / C_WIN (=2)
        ce[j] = __expf(-2.0f * dc * dc);
    }

    float4 qg[KWIN];
    unsigned vmask = 0;
    #pragma unroll
    for (int i = 0; i < 3; ++i) {
        #pragma unroll
        for (int j = 0; j < 5; ++j) {
            const int k  = i * 5 + j;
            const int rr = rowidx[i];
            const int cc = colidx[j];
            float4 v = make_float4(0.f, 0.f, 0.f, 0.f);
            if ((rr != 0) && (cc != 0)) {               // wave-uniform
                v = *reinterpret_cast<const float4*>(
                    &q[((size_t)((b * HGRID + rr - 1) * WGRID + cc - 1)) * DDIM
                       + lane * 4]);
                asm volatile("" : "+v"(v.x), "+v"(v.y), "+v"(v.z), "+v"(v.w));
                vmask |= (1u << k);
            }
            qg[k] = v;
        }
    }

    // ---------------- Step 2 (Phase A): slim MFMA proj ----------------
    f32x4 acc0 = (f32x4)0.f;
    f32x4 acc1 = (f32x4)0.f;

    const ushort* chp = &CH[(size_t)(pid0 + (l15 & 7)) * DDIM + g * 8];
    const ushort* clp = &CL[(size_t)(pid0 + (l15 & 7)) * DDIM + g * 8];
    const ushort* wh0 = &WHT[(size_t)(dq + l15) * DDIM + g * 8];
    const ushort* wl0 = &WLT[(size_t)(dq + l15) * DDIM + g * 8];
    const ushort* wh1 = wh0 + (size_t)16 * DDIM;
    const ushort* wl1 = wl0 + (size_t)16 * DDIM;

    #pragma unroll 1
    for (int kt = 0; kt < 8; ++kt) {
        union { uint4 u; bf16x8 v; } AH, AL, BH0, BL0, BH1, BL1;
        AH.u  = *reinterpret_cast<const uint4*>(chp + kt * 32);
        AL.u  = *reinterpret_cast<const uint4*>(clp + kt * 32);
        BH0.u = *reinterpret_cast<const uint4*>(wh0 + kt * 32);
        BL0.u = *reinterpret_cast<const uint4*>(wl0 + kt * 32);
        BH1.u = *reinterpret_cast<const uint4*>(wh1 + kt * 32);
        BL1.u = *reinterpret_cast<const uint4*>(wl1 + kt * 32);
        acc0 = __builtin_amdgcn_mfma_f32_16x16x32_bf16(AH.v, BH0.v, acc0, 0, 0, 0);
        acc0 = __builtin_amdgcn_mfma_f32_16x16x32_bf16(AH.v, BL0.v, acc0, 0, 0, 0);
        acc0 = __builtin_amdgcn_mfma_f32_16x16x32_bf16(AL.v, BH0.v, acc0, 0, 0, 0);
        acc1 = __builtin_amdgcn_mfma_f32_16x16x32_bf16(AH.v, BH1.v, acc1, 0, 0, 0);
        acc1 = __builtin_amdgcn_mfma_f32_16x16x32_bf16(AH.v, BL1.v, acc1, 0, 0, 0);
        acc1 = __builtin_amdgcn_mfma_f32_16x16x32_bf16(AL.v, BH1.v, acc1, 0, 0, 0);
    }

    // C/D layout: col = lane&15, row = (lane>>4)*4 + reg  [m89-verified]
    // Only rows 0..7 are real points (g < 2).
    if (g < 2) {
        #pragma unroll
        for (int r = 0; r < 4; ++r) {
            Pr[g * 4 + r][dq +  0 + l15] = acc0[r];
            Pr[g * 4 + r][dq + 16 + l15] = acc1[r];
        }
    }
    __syncthreads();

    // ---------------- Step 3 (Phase B): attention from registers ----------
    const float4 pr = *reinterpret_cast<const float4*>(&Pr[w][lane * 4]);

    float score[KWIN];
    #pragma unroll
    for (int k = 0; k < KWIN; ++k) {
        const float4 v = qg[k];
        score[k] = fmaf(v.x, pr.x, fmaf(v.y, pr.y, fmaf(v.z, pr.z, v.w * pr.w)));
    }

    // 15 independent butterfly reductions (pipelined)
    #pragma unroll
    for (int k = 0; k < KWIN; ++k) {
        float s = score[k];
        #pragma unroll
        for (int off = 32; off; off >>= 1) s += __shfl_xor(s, off, 64);
        score[k] = ((vmask >> k) & 1u) ? s : -INFINITY;
    }

    // Softmax over K=15 (replicated across lanes)
    float mx = score[0];
    #pragma unroll
    for (int k = 1; k < KWIN; ++k) mx = fmaxf(mx, score[k]);
    float sum = 0.f;
    #pragma unroll
    for (int k = 0; k < KWIN; ++k) {
        const float e = __expf(score[k] - mx);
        score[k] = e;
        sum += e;
    }
    const float inv = 1.0f / sum;

    // Weighted sum from registers
    float ox = 0.f, oy = 0.f, oz = 0.f, ow = 0.f;
    #pragma unroll
    for (int i = 0; i < 3; ++i) {
        #pragma unroll
        for (int j = 0; j < 5; ++j) {
            const int k = i * 5 + j;
            const float wk = score[k] * inv * re[i] * ce[j];
            ox = fmaf(wk, qg[k].x, ox);
            oy = fmaf(wk, qg[k].y, oy);
            oz = fmaf(wk, qg[k].z, oz);
            ow = fmaf(wk, qg[k].w, ow);
        }
    }
    *reinterpret_cast<float4*>(&out[(size_t)pid * DDIM + lane * 4]) =
        make_float4(ox, oy, oz, ow);
}

// ---------------------------------------------------------------------------
extern "C" void kernel_launch(void* const* d_in, const int* in_sizes, int n_in,
                              void* d_out, int out_size, void* d_ws, size_t ws_size,
                              hipStream_t stream) {
    const float* q   = (const float*)d_in[0];
    const float* c_t = (const float*)d_in[1];
    const float* p_t = (const float*)d_in[2];
    const float* W_a = (const float*)d_in[3];
    float* out = (float*)d_out;

    char* ws = (char*)d_ws;
    ushort* CH  = (ushort*)ws;                              // 4 MB
    ushort* CL  = (ushort*)(ws + (4 << 20));                // 4 MB
    ushort* WHT = (ushort*)(ws + (8 << 20));                // 128 KB
    ushort* WLT = (ushort*)(ws + (8 << 20) + DDIM * DDIM * 2);

    prep<<<CT_BLOCKS + DDIM, 256, 0, stream>>>(c_t, W_a, CH, CL, WHT, WLT);

    fused_local_attn<<<BN / PIDS_PER_BLK, THREADS, 0, stream>>>(
        q, p_t, CH, CL, WHT, WLT, out);
}

// Round 10
// 53.087 us; speedup vs baseline: 1.4670x; 1.4670x over previous
//
#include <hip/hip_runtime.h>
#include <math.h>

// Problem constants (fixed shapes from reference)
#define BATCH   8
#define HGRID   64
#define WGRID   64
#define DDIM    256
#define NPTS    1024
#define ROWS    65          // HGRID + 1 (NaN pad row 0)
#define COLS    65
#define KWIN    15          // (2*R_WIN+1)*(2*C_WIN+1) = 3*5
#define BN      (BATCH*NPTS)

#define PIDS_PER_BLK 16
#define THREADS      512    // 8 waves; Phase B: 2 pids per wave (v2-proven)
#define PR_PITCH     260
#define CT_BLOCKS    (BN * DDIM / 1024)   // 2048

typedef __attribute__((ext_vector_type(8))) short bf16x8;
typedef __attribute__((ext_vector_type(4))) float f32x4;

// ---------------------------------------------------------------------------
// Kernel 1 (prep): split c_t -> CH/CL (bf16 hi + bf16 residual), and split +
// TRANSPOSE W_a -> WHT/WLT[d][c] so MFMA B-frags are 16B k-contiguous loads.
// Blocks 0..2047: c_t (256 thr x 4 floats). Blocks 2048..2303: W column d.
// (verbatim from R9 — correctness proven, absmax 0.0156)
// ---------------------------------------------------------------------------
__global__ __launch_bounds__(256) void prep(const float* __restrict__ ct,
                                            const float* __restrict__ W,
                                            ushort* __restrict__ CH,
                                            ushort* __restrict__ CL,
                                            ushort* __restrict__ WHT,
                                            ushort* __restrict__ WLT) {
    const int bid = blockIdx.x;
    if (bid < CT_BLOCKS) {
        const int i = (bid * 256 + threadIdx.x) * 4;
        const float4 v = *reinterpret_cast<const float4*>(&ct[i]);
        const float f[4] = {v.x, v.y, v.z, v.w};
        ushort h[4], l[4];
        #pragma unroll
        for (int e = 0; e < 4; ++e) {
            const unsigned u = __float_as_uint(f[e]);
            h[e] = (ushort)(u >> 16);
            const float res = f[e] - __uint_as_float(u & 0xFFFF0000u);
            l[e] = (ushort)(__float_as_uint(res) >> 16);
        }
        *reinterpret_cast<ushort4*>(&CH[i]) = make_ushort4(h[0], h[1], h[2], h[3]);
        *reinterpret_cast<ushort4*>(&CL[i]) = make_ushort4(l[0], l[1], l[2], l[3]);
    } else {
        const int d = bid - CT_BLOCKS;
        const int c = threadIdx.x;
        const float f = W[c * DDIM + d];
        const unsigned u = __float_as_uint(f);
        const float res = f - __uint_as_float(u & 0xFFFF0000u);
        WHT[d * DDIM + c] = (ushort)(u >> 16);
        WLT[d * DDIM + c] = (ushort)(__float_as_uint(res) >> 16);
    }
}

// ---------------------------------------------------------------------------
// Kernel 2 (fused v6) = v2 (36.4us, best) with ONE change: Phase A uses
// pre-converted CH/CL/WHT/WLT (6x uint4 loads + 6 MFMA per kt, natural
// unroll, zero conversion VALU). Phase B is v2 verbatim: 2 pids/wave.
// __launch_bounds__(512,4). Grid 512 blocks (16 pids each).
// ---------------------------------------------------------------------------
__global__ __launch_bounds__(THREADS, 4) void fused_local_attn(
        const float* __restrict__ q,
        const float* __restrict__ p_t,
        const ushort* __restrict__ CH,
        const ushort* __restrict__ CL,
        const ushort* __restrict__ WHT,
        const ushort* __restrict__ WLT,
        float* __restrict__ out) {

    __shared__ __align__(16) float Pr[PIDS_PER_BLK][PR_PITCH]; // 16.6 KB

    const int t    = threadIdx.x;
    const int w    = t >> 6;          // wave 0..7
    const int lane = t & 63;
    const int l15  = lane & 15;
    const int g    = lane >> 4;       // k-group 0..3
    const int pid0 = blockIdx.x * PIDS_PER_BLK;
    const int dq   = w * 32;          // this wave's 32-col d-slice

    // ---------------- Phase A: proj into LDS (no barriers) ----------------
    f32x4 acc0 = (f32x4)0.f;
    f32x4 acc1 = (f32x4)0.f;

    const ushort* chp = &CH[(size_t)(pid0 + l15) * DDIM + g * 8];
    const ushort* clp = &CL[(size_t)(pid0 + l15) * DDIM + g * 8];
    const ushort* wh0 = &WHT[(size_t)(dq + l15) * DDIM + g * 8];
    const ushort* wl0 = &WLT[(size_t)(dq + l15) * DDIM + g * 8];
    const ushort* wh1 = wh0 + (size_t)16 * DDIM;
    const ushort* wl1 = wl0 + (size_t)16 * DDIM;

    #pragma unroll
    for (int kt = 0; kt < 8; ++kt) {
        union { uint4 u; bf16x8 v; } AH, AL, BH0, BL0, BH1, BL1;
        AH.u  = *reinterpret_cast<const uint4*>(chp + kt * 32);
        AL.u  = *reinterpret_cast<const uint4*>(clp + kt * 32);
        BH0.u = *reinterpret_cast<const uint4*>(wh0 + kt * 32);
        BL0.u = *reinterpret_cast<const uint4*>(wl0 + kt * 32);
        BH1.u = *reinterpret_cast<const uint4*>(wh1 + kt * 32);
        BL1.u = *reinterpret_cast<const uint4*>(wl1 + kt * 32);
        acc0 = __builtin_amdgcn_mfma_f32_16x16x32_bf16(AH.v, BH0.v, acc0, 0, 0, 0);
        acc0 = __builtin_amdgcn_mfma_f32_16x16x32_bf16(AH.v, BL0.v, acc0, 0, 0, 0);
        acc0 = __builtin_amdgcn_mfma_f32_16x16x32_bf16(AL.v, BH0.v, acc0, 0, 0, 0);
        acc1 = __builtin_amdgcn_mfma_f32_16x16x32_bf16(AH.v, BH1.v, acc1, 0, 0, 0);
        acc1 = __builtin_amdgcn_mfma_f32_16x16x32_bf16(AH.v, BL1.v, acc1, 0, 0, 0);
        acc1 = __builtin_amdgcn_mfma_f32_16x16x32_bf16(AL.v, BH1.v, acc1, 0, 0, 0);
    }

    // C/D layout: col = lane&15, row = (lane>>4)*4 + reg  [m89-verified]
    #pragma unroll
    for (int r = 0; r < 4; ++r) {
        Pr[g * 4 + r][dq +  0 + l15] = acc0[r];
        Pr[g * 4 + r][dq + 16 + l15] = acc1[r];
    }
    __syncthreads();

    // ---------------- Phase B: attention, 2 pids per wave (v2 verbatim) ---
    #pragma unroll 1
    for (int pp = 0; pp < 2; ++pp) {
        const int pl  = w * 2 + pp;            // pid-local 0..15
        const int pid = pid0 + pl;
        const int b   = pid >> 10;             // / NPTS
        const float2 ppos = *reinterpret_cast<const float2*>(&p_t[pid * 2]);
        const float p0f = ppos.x;
        const float p1f = ppos.y;
        const int p0 = (int)p0f;
        const int p1 = (int)p1f;

        const float4 pr = *reinterpret_cast<const float4*>(&Pr[pl][lane * 4]);

        float re[3], ce[5];
        int rowidx[3], colidx[5];
        #pragma unroll
        for (int i = 0; i < 3; ++i) {
            int rr = p0 + i;
            rr = rr > ROWS ? ROWS : rr;
            rr = (rr == ROWS) ? 0 : rr;        // % ROWS
            rowidx[i] = rr;
            const float rf = (float)(rr - 1 > 0 ? rr - 1 : 0);
            const float dr = rf - p0f;         // / R_WIN (=1)
            re[i] = __expf(-2.0f * dr * dr);
        }
        #pragma unroll
        for (int j = 0; j < 5; ++j) {
            int cc = p1 + j - 1;
            cc = cc < 0 ? 0 : (cc > COLS ? COLS : cc);
            cc = (cc == COLS) ? 0 : cc;        // % COLS
            colidx[j] = cc;
            const float cf = (float)(cc - 1 > 0 ? cc - 1 : 0);
            const float dc = (cf - p1f) * 0.5f; // / C_WIN (=2)
            ce[j] = __expf(-2.0f * dc * dc);
        }

        float4 qg[KWIN];
        float score[KWIN];
        unsigned vmask = 0;

        #pragma unroll
        for (int i = 0; i < 3; ++i) {
            #pragma unroll
            for (int j = 0; j < 5; ++j) {
                const int k  = i * 5 + j;
                const int rr = rowidx[i];
                const int cc = colidx[j];
                const bool valid = (rr != 0) && (cc != 0);   // wave-uniform
                float s = 0.f;
                float4 v = make_float4(0.f, 0.f, 0.f, 0.f);
                if (valid) {
                    v = *reinterpret_cast<const float4*>(
                        &q[((size_t)((b * HGRID + rr - 1) * WGRID + cc - 1)) * DDIM
                           + lane * 4]);
                    s = fmaf(v.x, pr.x, fmaf(v.y, pr.y, fmaf(v.z, pr.z, v.w * pr.w)));
                    vmask |= (1u << k);
                }
                qg[k] = v;
                score[k] = s;
            }
        }

        #pragma unroll
        for (int k = 0; k < KWIN; ++k) {
            float s = score[k];
            #pragma unroll
            for (int off = 32; off; off >>= 1) s += __shfl_xor(s, off, 64);
            score[k] = ((vmask >> k) & 1u) ? s : -INFINITY;
        }

        float mx = score[0];
        #pragma unroll
        for (int k = 1; k < KWIN; ++k) mx = fmaxf(mx, score[k]);
        float sum = 0.f;
        #pragma unroll
        for (int k = 0; k < KWIN; ++k) {
            const float e = __expf(score[k] - mx);
            score[k] = e;
            sum += e;
        }
        const float inv = 1.0f / sum;

        float ox = 0.f, oy = 0.f, oz = 0.f, ow = 0.f;
        #pragma unroll
        for (int i = 0; i < 3; ++i) {
            #pragma unroll
            for (int j = 0; j < 5; ++j) {
                const int k = i * 5 + j;
                const float wk = score[k] * inv * re[i] * ce[j];
                ox = fmaf(wk, qg[k].x, ox);
                oy = fmaf(wk, qg[k].y, oy);
                oz = fmaf(wk, qg[k].z, oz);
                ow = fmaf(wk, qg[k].w, ow);
            }
        }
        *reinterpret_cast<float4*>(&out[(size_t)pid * DDIM + lane * 4]) =
            make_float4(ox, oy, oz, ow);
    }
}

// ---------------------------------------------------------------------------
extern "C" void kernel_launch(void* const* d_in, const int* in_sizes, int n_in,
                              void* d_out, int out_size, void* d_ws, size_t ws_size,
                              hipStream_t stream) {
    const float* q   = (const float*)d_in[0];
    const float* c_t = (const float*)d_in[1];
    const float* p_t = (const float*)d_in[2];
    const float* W_a = (const float*)d_in[3];
    float* out = (float*)d_out;

    char* ws = (char*)d_ws;
    ushort* CH  = (ushort*)ws;                              // 4 MB
    ushort* CL  = (ushort*)(ws + (4 << 20));                // 4 MB
    ushort* WHT = (ushort*)(ws + (8 << 20));                // 128 KB
    ushort* WLT = (ushort*)(ws + (8 << 20) + DDIM * DDIM * 2);

    prep<<<CT_BLOCKS + DDIM, 256, 0, stream>>>(c_t, W_a, CH, CL, WHT, WLT);

    fused_local_attn<<<BN / PIDS_PER_BLK, THREADS, 0, stream>>>(
        q, p_t, CH, CL, WHT, WLT, out);
}

// Round 11
// 49.805 us; speedup vs baseline: 1.5637x; 1.0659x over previous
//
#include <hip/hip_runtime.h>
#include <math.h>

// Problem constants (fixed shapes from reference)
#define BATCH   8
#define HGRID   64
#define WGRID   64
#define DDIM    256
#define NPTS    1024
#define ROWS    65          // HGRID + 1 (NaN pad row 0)
#define COLS    65
#define KWIN    15          // (2*R_WIN+1)*(2*C_WIN+1) = 3*5
#define BN      (BATCH*NPTS)
#define APB     4           // attn: pids per block (4 waves x 1 pid)

typedef __attribute__((ext_vector_type(8))) short bf16x8;
typedef __attribute__((ext_vector_type(4))) float f32x4;

// Direct-to-LDS 16B/lane load: dest = ldsbase + lane*16 (wave-linear).
__device__ __forceinline__ void gload_lds16(const float* src, float* dst) {
    __builtin_amdgcn_global_load_lds(
        (const __attribute__((address_space(1))) unsigned int*)src,
        (__attribute__((address_space(3))) unsigned int*)dst, 16, 0, 0);
}

// ---------------------------------------------------------------------------
// Kernel 1: W_a[c][d] -> WHT[d][c], WLT[d][c] (bf16 hi + bf16 residual).
// 32x32 LDS tile transpose: coalesced read AND write. Grid (8,8).
// ---------------------------------------------------------------------------
__global__ __launch_bounds__(256) void prep_w(const float* __restrict__ W,
                                              ushort* __restrict__ WHT,
                                              ushort* __restrict__ WLT) {
    __shared__ float Ls[32][33];
    const int t  = threadIdx.x;
    const int tx = t & 31;
    const int ty = t >> 5;              // 0..7
    const int d0 = blockIdx.x * 32;
    const int c0 = blockIdx.y * 32;
    #pragma unroll
    for (int r = 0; r < 4; ++r) {
        const int row = ty + r * 8;
        Ls[row][tx] = W[(c0 + row) * DDIM + d0 + tx];
    }
    __syncthreads();
    #pragma unroll
    for (int r = 0; r < 4; ++r) {
        const int row = ty + r * 8;     // d-local
        const float f = Ls[tx][row];    // = W[c0+tx][d0+row]
        const unsigned u = __float_as_uint(f);
        const float res = f - __uint_as_float(u & 0xFFFF0000u);
        WHT[(d0 + row) * DDIM + c0 + tx] = (ushort)(u >> 16);
        WLT[(d0 + row) * DDIM + c0 + tx] = (ushort)(__float_as_uint(res) >> 16);
    }
}

// ---------------------------------------------------------------------------
// Kernel 2: proj = c_t x W_a, 3-term split-bf16 MFMA (R7 tile + inline A
// conversion from fp32 c_t). Block 256 (4 waves), BM=64, BN=64, grid (128,4).
// ---------------------------------------------------------------------------
__global__ __launch_bounds__(256) void proj_gemm(const float* __restrict__ C,
                                                 const ushort* __restrict__ WHT,
                                                 const ushort* __restrict__ WLT,
                                                 float* __restrict__ P) {
    __shared__ __align__(16) ushort BHs[64][40];   // [col][k] pitch 80B
    __shared__ __align__(16) ushort BLs[64][40];

    const int t    = threadIdx.x;
    const int wv   = t >> 6;
    const int lane = t & 63;
    const int l15  = lane & 15;
    const int g    = lane >> 4;            // k-subgroup 0..3
    const int m0   = blockIdx.x * 64;
    const int n0   = blockIdx.y * 64;
    const int scol  = t >> 2;              // staging: col 0..63
    const int spart = t & 3;               // staging: k-part (8 ushorts)

    f32x4 acc[4];
    #pragma unroll
    for (int df = 0; df < 4; ++df) acc[df] = (f32x4)0.0f;

    const int arow = m0 + wv * 16 + l15;

    for (int kt = 0; kt < 8; ++kt) {
        __syncthreads();
        *reinterpret_cast<uint4*>(&BHs[scol][spart * 8]) =
            *reinterpret_cast<const uint4*>(&WHT[(n0 + scol) * DDIM + kt * 32 + spart * 8]);
        *reinterpret_cast<uint4*>(&BLs[scol][spart * 8]) =
            *reinterpret_cast<const uint4*>(&WLT[(n0 + scol) * DDIM + kt * 32 + spart * 8]);
        __syncthreads();

        // A fragment: fp32 load + inline split (v2-proven)
        const float* ap = &C[(size_t)arow * DDIM + kt * 32 + g * 8];
        const float4 a01 = *reinterpret_cast<const float4*>(ap);
        const float4 a23 = *reinterpret_cast<const float4*>(ap + 4);
        const float af[8] = {a01.x, a01.y, a01.z, a01.w, a23.x, a23.y, a23.z, a23.w};
        union { bf16x8 v; unsigned u[4]; } AH, AL;
        #pragma unroll
        for (int i = 0; i < 4; ++i) {
            const unsigned u0 = __float_as_uint(af[2 * i]);
            const unsigned u1 = __float_as_uint(af[2 * i + 1]);
            AH.u[i] = __builtin_amdgcn_perm(u1, u0, 0x07060302u);
            const float l0 = af[2 * i]     - __uint_as_float(u0 & 0xFFFF0000u);
            const float l1 = af[2 * i + 1] - __uint_as_float(u1 & 0xFFFF0000u);
            AL.u[i] = __builtin_amdgcn_perm(__float_as_uint(l1), __float_as_uint(l0),
                                            0x07060302u);
        }

        #pragma unroll
        for (int df = 0; df < 4; ++df) {
            union { uint4 u; bf16x8 v; } BH, BL;
            BH.u = *reinterpret_cast<const uint4*>(&BHs[df * 16 + l15][g * 8]);
            BL.u = *reinterpret_cast<const uint4*>(&BLs[df * 16 + l15][g * 8]);
            acc[df] = __builtin_amdgcn_mfma_f32_16x16x32_bf16(AH.v, BH.v, acc[df], 0, 0, 0);
            acc[df] = __builtin_amdgcn_mfma_f32_16x16x32_bf16(AH.v, BL.v, acc[df], 0, 0, 0);
            acc[df] = __builtin_amdgcn_mfma_f32_16x16x32_bf16(AL.v, BH.v, acc[df], 0, 0, 0);
        }
    }

    // C/D layout: col = lane&15, row = (lane>>4)*4 + reg  [m89-verified]
    #pragma unroll
    for (int df = 0; df < 4; ++df)
        #pragma unroll
        for (int r = 0; r < 4; ++r)
            P[(size_t)(m0 + wv * 16 + g * 4 + r) * DDIM + n0 + df * 16 + l15] = acc[df][r];
}

// ---------------------------------------------------------------------------
// Kernel 3: local attention, 1 wave per pid, gathers staged via
// global_load_lds (no VGPR pressure -> all 15 loads concurrently in flight,
// ONE vmcnt(0) wait). 4 pids/block, 60KB LDS, grid 2048.
// ---------------------------------------------------------------------------
__global__ __launch_bounds__(256) void local_attn(const float* __restrict__ q,
                                                  const float* __restrict__ p_t,
                                                  const float* __restrict__ proj,
                                                  float* __restrict__ out) {
    __shared__ __align__(16) float qs[APB][KWIN][DDIM];   // 61440 B

    const int w    = threadIdx.x >> 6;
    const int lane = threadIdx.x & 63;
    const int pid  = blockIdx.x * APB + w;
    const int b    = pid >> 10;
    const float2 pp = *reinterpret_cast<const float2*>(&p_t[pid * 2]);
    const float p0f = pp.x;
    const float p1f = pp.y;
    const int p0 = (int)p0f;
    const int p1 = (int)p1f;

    // proj row load goes in flight alongside the gathers
    const float4 pr = *reinterpret_cast<const float4*>(&proj[(size_t)pid * DDIM + lane * 4]);

    float re[3], ce[5];
    int rowidx[3], colidx[5];
    #pragma unroll
    for (int i = 0; i < 3; ++i) {
        int rr = p0 + i;
        rr = rr > ROWS ? ROWS : rr;
        rr = (rr == ROWS) ? 0 : rr;        // % ROWS
        rowidx[i] = rr;
        const float rf = (float)(rr - 1 > 0 ? rr - 1 : 0);
        const float dr = rf - p0f;         // / R_WIN (=1)
        re[i] = __expf(-2.0f * dr * dr);
    }
    #pragma unroll
    for (int j = 0; j < 5; ++j) {
        int cc = p1 + j - 1;
        cc = cc < 0 ? 0 : (cc > COLS ? COLS : cc);
        cc = (cc == COLS) ? 0 : cc;        // % COLS
        colidx[j] = cc;
        const float cf = (float)(cc - 1 > 0 ? cc - 1 : 0);
        const float dc = (cf - p1f) * 0.5f; // / C_WIN (=2)
        ce[j] = __expf(-2.0f * dc * dc);
    }

    // ---- Issue all valid gathers direct-to-LDS (no VGPR round trip) ----
    unsigned vmask = 0;
    #pragma unroll
    for (int i = 0; i < 3; ++i) {
        #pragma unroll
        for (int j = 0; j < 5; ++j) {
            const int k  = i * 5 + j;
            const int rr = rowidx[i];
            const int cc = colidx[j];
            if ((rr != 0) && (cc != 0)) {               // wave-uniform
                gload_lds16(&q[((size_t)((b * HGRID + rr - 1) * WGRID + cc - 1)) * DDIM
                               + lane * 4],
                            &qs[w][k][0]);
                vmask |= (1u << k);
            }
        }
    }
    asm volatile("s_waitcnt vmcnt(0)" ::: "memory");    // one wait for all 15

    // ---- Scores from LDS ----
    float score[KWIN];
    #pragma unroll
    for (int k = 0; k < KWIN; ++k) {
        float s = 0.f;
        if ((vmask >> k) & 1u) {
            const float4 v = *reinterpret_cast<const float4*>(&qs[w][k][lane * 4]);
            s = fmaf(v.x, pr.x, fmaf(v.y, pr.y, fmaf(v.z, pr.z, v.w * pr.w)));
        }
        score[k] = s;
    }

    // ---- 15 independent butterfly reductions ----
    #pragma unroll
    for (int k = 0; k < KWIN; ++k) {
        float s = score[k];
        #pragma unroll
        for (int off = 32; off; off >>= 1) s += __shfl_xor(s, off, 64);
        score[k] = ((vmask >> k) & 1u) ? s : -INFINITY;
    }

    // ---- Softmax over K=15 (replicated across lanes) ----
    float mx = score[0];
    #pragma unroll
    for (int k = 1; k < KWIN; ++k) mx = fmaxf(mx, score[k]);
    float sum = 0.f;
    #pragma unroll
    for (int k = 0; k < KWIN; ++k) {
        const float e = __expf(score[k] - mx);
        score[k] = e;
        sum += e;
    }
    const float inv = 1.0f / sum;

    // ---- Weighted sum (re-read LDS; cheap) ----
    float ox = 0.f, oy = 0.f, oz = 0.f, ow = 0.f;
    #pragma unroll
    for (int i = 0; i < 3; ++i) {
        #pragma unroll
        for (int j = 0; j < 5; ++j) {
            const int k = i * 5 + j;
            if ((vmask >> k) & 1u) {
                const float4 v = *reinterpret_cast<const float4*>(&qs[w][k][lane * 4]);
                const float wk = score[k] * inv * re[i] * ce[j];
                ox = fmaf(wk, v.x, ox);
                oy = fmaf(wk, v.y, oy);
                oz = fmaf(wk, v.z, oz);
                ow = fmaf(wk, v.w, ow);
            }
        }
    }
    *reinterpret_cast<float4*>(&out[(size_t)pid * DDIM + lane * 4]) =
        make_float4(ox, oy, oz, ow);
}

// ---------------------------------------------------------------------------
extern "C" void kernel_launch(void* const* d_in, const int* in_sizes, int n_in,
                              void* d_out, int out_size, void* d_ws, size_t ws_size,
                              hipStream_t stream) {
    const float* q   = (const float*)d_in[0];
    const float* c_t = (const float*)d_in[1];
    const float* p_t = (const float*)d_in[2];
    const float* W_a = (const float*)d_in[3];
    float* out = (float*)d_out;

    char* ws = (char*)d_ws;
    float*  proj = (float*)ws;                              // 8 MB
    ushort* WHT  = (ushort*)(ws + (8 << 20));               // 128 KB
    ushort* WLT  = (ushort*)(ws + (8 << 20) + DDIM * DDIM * 2);

    dim3 wgrid(8, 8);
    prep_w<<<wgrid, 256, 0, stream>>>(W_a, WHT, WLT);

    dim3 ggrid(BN / 64, DDIM / 64);                         // 128 x 4
    proj_gemm<<<ggrid, 256, 0, stream>>>(c_t, WHT, WLT, proj);

    local_attn<<<BN / APB, 256, 0, stream>>>(q, p_t, proj, out);
}

// Round 12
// 35.514 us; speedup vs baseline: 2.1930x; 1.4024x over previous
//
#include <hip/hip_runtime.h>
#include <math.h>

// Problem constants (fixed shapes from reference)
#define BATCH   8
#define HGRID   64
#define WGRID   64
#define DDIM    256
#define NPTS    1024
#define ROWS    65          // HGRID + 1 (NaN pad row 0)
#define COLS    65
#define KWIN    15          // (2*R_WIN+1)*(2*C_WIN+1) = 3*5
#define BN      (BATCH*NPTS)

#define PIDS_PER_BLK 16
#define THREADS      512    // 8 waves; Phase B: 2 pids per wave

typedef __attribute__((ext_vector_type(8))) short bf16x8;
typedef __attribute__((ext_vector_type(4))) float f32x4;

// Direct-to-LDS 16B/lane: dest = wave-uniform base + lane*16.
__device__ __forceinline__ void gload_lds16(const float* src, float* dst) {
    __builtin_amdgcn_global_load_lds(
        (const __attribute__((address_space(1))) unsigned int*)src,
        (__attribute__((address_space(3))) unsigned int*)dst, 16, 0, 0);
}

// ---------------------------------------------------------------------------
// Fused v7 = v2 (36.4us best) with ONE change: Phase B gather engine.
// Per pid: rows 0-7 -> registers, rows 8-14 -> global_load_lds; all 15
// loads concurrently in flight, ONE s_waitcnt vmcnt(0); regs pinned once
// AFTER the drain (no per-load fences -> no serialization); no remat.
// LDS: Pr[16][256] (Phase A handoff, 16KB) aliases qs[8][7][256] (56KB) --
// Pr is dead once each wave snapshots its two pr rows.
// ---------------------------------------------------------------------------
__global__ __launch_bounds__(THREADS, 4) void fused_local_attn(
        const float* __restrict__ q,
        const float* __restrict__ c_t,
        const float* __restrict__ p_t,
        const float* __restrict__ W,
        float* __restrict__ out) {

    __shared__ __align__(16) float smem[14336];   // 56 KB
    float (*Pr)[DDIM] = reinterpret_cast<float (*)[DDIM]>(smem);

    const int t    = threadIdx.x;
    const int w    = t >> 6;          // wave 0..7
    const int lane = t & 63;
    const int l15  = lane & 15;
    const int g    = lane >> 4;       // k-group 0..3
    const int pid0 = blockIdx.x * PIDS_PER_BLK;
    const int dq   = w * 32;          // this wave's 32-col d-slice
    float* qsw = smem + w * (7 * DDIM);   // this wave's 7-row staging slab

    // ---------------- Phase A: proj into LDS (v2 verbatim) ----------------
    f32x4 acc0 = (f32x4)0.f;
    f32x4 acc1 = (f32x4)0.f;

    const float* ap  = &c_t[(size_t)(pid0 + l15) * DDIM + g * 8];
    const float* wp0 = &W[(size_t)(g * 8) * DDIM + dq + l15];        // df=0
    const float* wp1 = wp0 + 16;                                      // df=1

    #pragma unroll 2
    for (int kt = 0; kt < 8; ++kt) {
        const float4 a01 = *reinterpret_cast<const float4*>(ap + kt * 32);
        const float4 a23 = *reinterpret_cast<const float4*>(ap + kt * 32 + 4);
        const float af[8] = {a01.x, a01.y, a01.z, a01.w, a23.x, a23.y, a23.z, a23.w};
        union { bf16x8 v; unsigned u[4]; } AH, AL;
        #pragma unroll
        for (int i = 0; i < 4; ++i) {
            const unsigned u0 = __float_as_uint(af[2 * i]);
            const unsigned u1 = __float_as_uint(af[2 * i + 1]);
            AH.u[i] = __builtin_amdgcn_perm(u1, u0, 0x07060302u);
            const float l0 = af[2 * i]     - __uint_as_float(u0 & 0xFFFF0000u);
            const float l1 = af[2 * i + 1] - __uint_as_float(u1 & 0xFFFF0000u);
            AL.u[i] = __builtin_amdgcn_perm(__float_as_uint(l1), __float_as_uint(l0),
                                            0x07060302u);
        }

        #pragma unroll
        for (int df = 0; df < 2; ++df) {
            const float* wp = (df == 0) ? wp0 : wp1;
            float bf[8];
            #pragma unroll
            for (int i = 0; i < 8; ++i)
                bf[i] = wp[(size_t)(kt * 32 + i) * DDIM];
            union { bf16x8 v; unsigned u[4]; } BH, BL;
            #pragma unroll
            for (int i = 0; i < 4; ++i) {
                const unsigned u0 = __float_as_uint(bf[2 * i]);
                const unsigned u1 = __float_as_uint(bf[2 * i + 1]);
                BH.u[i] = __builtin_amdgcn_perm(u1, u0, 0x07060302u);
                const float l0 = bf[2 * i]     - __uint_as_float(u0 & 0xFFFF0000u);
                const float l1 = bf[2 * i + 1] - __uint_as_float(u1 & 0xFFFF0000u);
                BL.u[i] = __builtin_amdgcn_perm(__float_as_uint(l1), __float_as_uint(l0),
                                                0x07060302u);
            }
            f32x4 a = (df == 0) ? acc0 : acc1;
            a = __builtin_amdgcn_mfma_f32_16x16x32_bf16(AH.v, BH.v, a, 0, 0, 0);
            a = __builtin_amdgcn_mfma_f32_16x16x32_bf16(AH.v, BL.v, a, 0, 0, 0);
            a = __builtin_amdgcn_mfma_f32_16x16x32_bf16(AL.v, BH.v, a, 0, 0, 0);
            if (df == 0) acc0 = a; else acc1 = a;
        }
    }

    // C/D layout: col = lane&15, row = (lane>>4)*4 + reg  [m89-verified]
    #pragma unroll
    for (int r = 0; r < 4; ++r) {
        Pr[g * 4 + r][dq +  0 + l15] = acc0[r];
        Pr[g * 4 + r][dq + 16 + l15] = acc1[r];
    }
    __syncthreads();

    // Snapshot both pr rows, then Pr's LDS is recycled as staging space.
    const float4 prA = *reinterpret_cast<const float4*>(&Pr[w * 2 + 0][lane * 4]);
    const float4 prB = *reinterpret_cast<const float4*>(&Pr[w * 2 + 1][lane * 4]);
    __syncthreads();

    // ---------------- Phase B: attention, 2 pids per wave -----------------
    #pragma unroll 1
    for (int pp = 0; pp < 2; ++pp) {
        const int pl  = w * 2 + pp;            // pid-local 0..15
        const int pid = pid0 + pl;
        const int b   = pid >> 10;             // / NPTS
        const float4 pr = pp ? prB : prA;
        const float2 ppos = *reinterpret_cast<const float2*>(&p_t[pid * 2]);
        const float p0f = ppos.x;
        const float p1f = ppos.y;
        const int p0 = (int)p0f;
        const int p1 = (int)p1f;

        float re[3], ce[5];
        int rowidx[3], colidx[5];
        #pragma unroll
        for (int i = 0; i < 3; ++i) {
            int rr = p0 + i;
            rr = rr > ROWS ? ROWS : rr;
            rr = (rr == ROWS) ? 0 : rr;        // % ROWS
            rowidx[i] = rr;
            const float rf = (float)(rr - 1 > 0 ? rr - 1 : 0);
            const float dr = rf - p0f;         // / R_WIN (=1)
            re[i] = __expf(-2.0f * dr * dr);
        }
        #pragma unroll
        for (int j = 0; j < 5; ++j) {
            int cc = p1 + j - 1;
            cc = cc < 0 ? 0 : (cc > COLS ? COLS : cc);
            cc = (cc == COLS) ? 0 : cc;        // % COLS
            colidx[j] = cc;
            const float cf = (float)(cc - 1 > 0 ? cc - 1 : 0);
            const float dc = (cf - p1f) * 0.5f; // / C_WIN (=2)
            ce[j] = __expf(-2.0f * dc * dc);
        }

        // Fence: previous round's LDS reads must retire before async writes
        // to the same slab can be issued (vmcnt and lgkmcnt are separate).
        asm volatile("s_waitcnt lgkmcnt(0)" ::: "memory");
        __builtin_amdgcn_sched_barrier(0);

        // ---- Issue ALL 15 gathers: rows 0-7 -> regs, 8-14 -> LDS ----
        float4 qg[8];
        unsigned vmask = 0;
        #pragma unroll
        for (int k = 0; k < KWIN; ++k) {
            const int i = k / 5, j = k % 5;
            const int rr = rowidx[i];
            const int cc = colidx[j];
            const bool valid = (rr != 0) && (cc != 0);   // wave-uniform
            const float* src =
                &q[((size_t)((b * HGRID + rr - 1) * WGRID + cc - 1)) * DDIM + lane * 4];
            if (k < 8) {
                float4 v = make_float4(0.f, 0.f, 0.f, 0.f);
                if (valid) v = *reinterpret_cast<const float4*>(src);
                qg[k] = v;
            } else {
                if (valid) gload_lds16(src, &qsw[(k - 8) * DDIM]);
            }
            if (valid) vmask |= (1u << k);
        }
        asm volatile("s_waitcnt vmcnt(0)" ::: "memory");   // ONE wait for all 15
        // Pin register rows once (post-drain: no serialization, no remat).
        #pragma unroll
        for (int k = 0; k < 8; ++k)
            asm volatile("" : "+v"(qg[k].x), "+v"(qg[k].y), "+v"(qg[k].z), "+v"(qg[k].w));

        // ---- Scores ----
        float score[KWIN];
        #pragma unroll
        for (int k = 0; k < 8; ++k) {
            const float4 v = qg[k];
            score[k] = fmaf(v.x, pr.x, fmaf(v.y, pr.y, fmaf(v.z, pr.z, v.w * pr.w)));
        }
        #pragma unroll
        for (int k = 8; k < KWIN; ++k) {
            const float4 v = *reinterpret_cast<const float4*>(&qsw[(k - 8) * DDIM + lane * 4]);
            score[k] = fmaf(v.x, pr.x, fmaf(v.y, pr.y, fmaf(v.z, pr.z, v.w * pr.w)));
        }

        // ---- 15 independent butterfly reductions ----
        #pragma unroll
        for (int k = 0; k < KWIN; ++k) {
            float s = score[k];
            #pragma unroll
            for (int off = 32; off; off >>= 1) s += __shfl_xor(s, off, 64);
            score[k] = ((vmask >> k) & 1u) ? s : -INFINITY;
        }

        // ---- Softmax over K=15 (replicated across lanes) ----
        float mx = score[0];
        #pragma unroll
        for (int k = 1; k < KWIN; ++k) mx = fmaxf(mx, score[k]);
        float sum = 0.f;
        #pragma unroll
        for (int k = 0; k < KWIN; ++k) {
            const float e = __expf(score[k] - mx);
            score[k] = e;
            sum += e;
        }
        const float inv = 1.0f / sum;

        // ---- Weighted sum: rows 0-7 from regs, 8-14 from LDS ----
        float ox = 0.f, oy = 0.f, oz = 0.f, ow = 0.f;
        #pragma unroll
        for (int k = 0; k < KWIN; ++k) {
            const int i = k / 5, j = k % 5;
            const float wk = score[k] * inv * re[i] * ce[j];
            if (k < 8) {
                ox = fmaf(wk, qg[k].x, ox);
                oy = fmaf(wk, qg[k].y, oy);
                oz = fmaf(wk, qg[k].z, oz);
                ow = fmaf(wk, qg[k].w, ow);
            } else if ((vmask >> k) & 1u) {   // guard: stale LDS may be NaN
                const float4 v =
                    *reinterpret_cast<const float4*>(&qsw[(k - 8) * DDIM + lane * 4]);
                ox = fmaf(wk, v.x, ox);
                oy = fmaf(wk, v.y, oy);
                oz = fmaf(wk, v.z, oz);
                ow = fmaf(wk, v.w, ow);
            }
        }
        *reinterpret_cast<float4*>(&out[(size_t)pid * DDIM + lane * 4]) =
            make_float4(ox, oy, oz, ow);
    }
}

// ---------------------------------------------------------------------------
extern "C" void kernel_launch(void* const* d_in, const int* in_sizes, int n_in,
                              void* d_out, int out_size, void* d_ws, size_t ws_size,
                              hipStream_t stream) {
    const float* q   = (const float*)d_in[0];
    const float* c_t = (const float*)d_in[1];
    const float* p_t = (const float*)d_in[2];
    const float* W_a = (const float*)d_in[3];
    float* out = (float*)d_out;

    fused_local_attn<<<BN / PIDS_PER_BLK, THREADS, 0, stream>>>(q, c_t, p_t, W_a, out);
}